// Round 4
// baseline (147.234 us; speedup 1.0000x reference)
//
#include <hip/hip_runtime.h>
#include <hip/hip_bf16.h>
#include <hip/hip_fp16.h>

// Problem constants
#define GN 28
// ws layout: per-g contiguous 12288-byte tile, pre-swizzled for LDS staging:
//   [ W1 f16 [n=64][k=64] 8KiB | W2 f16 [n2=32][kk=64] K-permuted 4KiB ]
// byte = n*128 + 2k, XOR-swizzled ^((n&7)<<4)   (byte-identical to r2/r3 layout)
#define G_TILE_BYTES 12288
#define WS_BYTES (GN * G_TILE_BYTES)   // 344064

typedef __attribute__((ext_vector_type(4))) float f32x4;
typedef __attribute__((ext_vector_type(8))) short short8;
typedef _Float16 f16x8 __attribute__((ext_vector_type(8)));

__device__ __forceinline__ unsigned short f2h(float v){
  __half h = __float2half(v);   // RNE
  return __builtin_bit_cast(unsigned short, h);
}
__device__ __forceinline__ f32x4 mfma16f(short8 a, short8 b, f32x4 c){
  return __builtin_amdgcn_mfma_f32_16x16x32_f16(
      __builtin_bit_cast(f16x8, a), __builtin_bit_cast(f16x8, b), c, 0, 0, 0);
}

// ---------------------------------------------------------------------------
// Prologue v2: one block per g, coalesced reads, LDS transpose (+1 pad),
// packed uint4 swizzle-safe stores. Output bytes identical to r2/r3 prologue.
// W2 K-permuted so layer-1 D-fragments feed layer-2 B directly:
//   MFMA k-slot kk = ks*32 + q*8 + u*4 + i  carries  kn = 32*ks + 16*u + 4*q + i
// ---------------------------------------------------------------------------
__global__ __launch_bounds__(256) void prep_weights(
    const float* __restrict__ W1, const float* __restrict__ W2,
    unsigned char* __restrict__ ws){
  __shared__ float t1[64*65];   // W1[g] transposed staging, padded
  __shared__ float t2[64*33];   // W2[g] staging, padded
  const int g = blockIdx.x;
  const int tid = threadIdx.x;

  // coalesced load W1[g] (4096 f32): 16 floats/thread, one k-row slice each
  {
    const f32x4* src = (const f32x4*)(W1 + g*4096);
    int k = tid >> 2, n0 = (tid & 3) * 16;
    #pragma unroll
    for (int j = 0; j < 4; ++j){
      f32x4 v = src[tid*4 + j];
      #pragma unroll
      for (int e = 0; e < 4; ++e) t1[k*65 + n0 + j*4 + e] = v[e];
    }
  }
  // coalesced load W2[g] (2048 f32): 8 floats/thread
  {
    const f32x4* src = (const f32x4*)(W2 + g*2048);
    int k = tid >> 2, n0 = (tid & 3) * 8;
    #pragma unroll
    for (int j = 0; j < 2; ++j){
      f32x4 v = src[tid*2 + j];
      #pragma unroll
      for (int e = 0; e < 4; ++e) t2[k*33 + n0 + j*4 + e] = v[e];
    }
  }
  __syncthreads();

  unsigned char* base = ws + g*G_TILE_BYTES;
  // W1 tile: thread owns (n = tid&63, mh = tid>>6); 8 packed words = 2 uint4
  {
    int n = tid & 63, mh = tid >> 6;
    #pragma unroll
    for (int h = 0; h < 2; ++h){
      unsigned w[4];
      #pragma unroll
      for (int mm = 0; mm < 4; ++mm){
        int m = mh*8 + h*4 + mm;          // k-pair index
        float lo = t1[(2*m    )*65 + n];
        float hi = t1[(2*m + 1)*65 + n];
        w[mm] = (unsigned)f2h(lo) | ((unsigned)f2h(hi) << 16);
      }
      int off = (n*128 + mh*32 + h*16) ^ ((n & 7) << 4);
      *(uint4*)(base + off) = make_uint4(w[0], w[1], w[2], w[3]);
    }
  }
  // W2 tile: thread owns (n2 = tid&31, mq = tid>>5); 4 packed words = 1 uint4
  {
    int n2 = tid & 31, mq = tid >> 5;
    unsigned w[4];
    #pragma unroll
    for (int mm = 0; mm < 4; ++mm){
      int m = mq*4 + mm;
      int kk = 2*m;
      int ks = kk >> 5, qq = (kk >> 3) & 3, u = (kk >> 2) & 1, i = kk & 3;
      int kn = 32*ks + 16*u + 4*qq + i;   // kk,kk+1 -> kn,kn+1
      float lo = t2[(kn    )*33 + n2];
      float hi = t2[(kn + 1)*33 + n2];
      w[mm] = (unsigned)f2h(lo) | ((unsigned)f2h(hi) << 16);
    }
    int off = (n2*128 + mq*16) ^ ((n2 & 7) << 4);
    *(uint4*)(base + 8192 + off) = make_uint4(w[0], w[1], w[2], w[3]);
  }
}

// ---------------------------------------------------------------------------
// Main fused kernel. 1024 blocks x 256 threads (4 waves), 128 rows/block,
// 32 rows/wave. LDS = 39 KB -> 4 independent blocks/CU (16 waves/CU) so
// blocks drift out of barrier phase and MFMA/VALU/LDS pipes overlap across
// blocks. Outputs stored directly to global (L2 aggregates); bias regs feed
// MFMA C-operand directly (no accumulator-init movs).
// ---------------------------------------------------------------------------
__global__ __launch_bounds__(256, 4) void mlp_fused(
    const float* __restrict__ x,  const float* __restrict__ b1,
    const float* __restrict__ b2, const float* __restrict__ W3,
    const float* __restrict__ b3, const unsigned char* __restrict__ ws,
    float* __restrict__ out){
  __shared__ uint4 wbuf[2][768];        // 2 x 12 KiB weight tile
  __shared__ float biasL[3616];         // b1[1792] | b2[896] | W3[896] | b3[28]

  const int tid = threadIdx.x;
  const int wv  = tid >> 6;
  const int ln  = tid & 63;
  const int l15 = ln & 15;
  const int q   = ln >> 4;
  const int rowBase = blockIdx.x * 128 + wv * 32;

  // ---- one-time bias/W3 preload into LDS ----
  #pragma unroll
  for (int i = 0; i < 7; ++i) biasL[i*256 + tid] = b1[i*256 + tid];
  #pragma unroll
  for (int i = 0; i < 4; ++i){
    int idx = i*256 + tid;
    if (idx < 896){
      biasL[1792 + idx] = b2[idx];
      biasL[2688 + idx] = W3[idx];
    }
  }
  if (tid < 28) biasL[3584 + tid] = b3[tid];

  // ---- x B-fragments (f16), loaded once, reused for all 28 g ----
  short8 xf[2][2];
  #pragma unroll
  for (int rt = 0; rt < 2; ++rt)
    #pragma unroll
    for (int ks = 0; ks < 2; ++ks){
      const float* p = x + (rowBase + rt*16 + l15)*64 + ks*32 + q*8;
      f32x4 a = *(const f32x4*)p;
      f32x4 b = *(const f32x4*)(p + 4);
      short8 s;
      #pragma unroll
      for (int j = 0; j < 4; ++j){
        s[j]   = (short)f2h(a[j]);
        s[4+j] = (short)f2h(b[j]);
      }
      xf[rt][ks] = s;
    }

  // ---- staging: wave wv copies its 3 KiB slice of g's 12 KiB tile ----
  auto stage = [&](int g, int buf){
    const unsigned char* gb = ws + g*G_TILE_BYTES + wv*3072 + ln*16;
    uint4* lb = &wbuf[buf][wv*192];
    #pragma unroll
    for (int it = 0; it < 3; ++it){
      __builtin_amdgcn_global_load_lds(
          (const __attribute__((address_space(1))) void*)(gb + it*1024),
          (__attribute__((address_space(3))) void*)(lb + it*64), 16, 0, 0);
    }
  };

  stage(0, 0);
  asm volatile("s_waitcnt vmcnt(0)" ::: "memory");
  __syncthreads();

  for (int g = 0; g < GN; ++g){
    const int cur = g & 1;
    if (g + 1 < GN) stage(g + 1, cur ^ 1);
    const uint4* wb = wbuf[cur];

    // bias fragments for this g (C-operands, no acc-init movs)
    f32x4 bias1[4], bias2[2], w3f[2];
    #pragma unroll
    for (int nt = 0; nt < 4; ++nt)
      bias1[nt] = *(const f32x4*)&biasL[g*64 + nt*16 + q*4];
    #pragma unroll
    for (int nt = 0; nt < 2; ++nt){
      bias2[nt] = *(const f32x4*)&biasL[1792 + g*32 + nt*16 + q*4];
      w3f[nt]   = *(const f32x4*)&biasL[2688 + g*32 + nt*16 + q*4];
    }
    float bias3 = biasL[3584 + g];

    // ---------------- layer 1: h1T[n=64][r=32/wave] ----------------
    short8 a1[4][2];
    #pragma unroll
    for (int nt = 0; nt < 4; ++nt)
      #pragma unroll
      for (int ks = 0; ks < 2; ++ks){
        int n = nt*16 + l15;
        int off = ((n*128 + ks*64 + q*16) ^ ((n & 7) << 4)) >> 4;
        a1[nt][ks] = __builtin_bit_cast(short8, wb[off]);
      }
    f32x4 acc1[4][2];
    #pragma unroll
    for (int nt = 0; nt < 4; ++nt)
      #pragma unroll
      for (int rt = 0; rt < 2; ++rt){
        acc1[nt][rt] = mfma16f(a1[nt][0], xf[rt][0], bias1[nt]);
        acc1[nt][rt] = mfma16f(a1[nt][1], xf[rt][1], acc1[nt][rt]);
      }

    // ---- h1 relu -> f16, packed IN REGISTERS as layer-2 B-frags ----
    // k-slot (ks, q*8+u*4+i) carries n = 32ks+16u+4q+i == acc1[2ks+u][rt][i]
    short8 bh[2][2];
    #pragma unroll
    for (int rt = 0; rt < 2; ++rt)
      #pragma unroll
      for (int ks = 0; ks < 2; ++ks){
        f32x4 v0 = acc1[2*ks][rt], v1 = acc1[2*ks + 1][rt];
        short8 h;
        #pragma unroll
        for (int i = 0; i < 4; ++i){
          h[i]   = (short)f2h(fmaxf(v0[i], 0.0f));
          h[4+i] = (short)f2h(fmaxf(v1[i], 0.0f));
        }
        bh[rt][ks] = h;
      }

    // ---------------- layer 2: h2T[n2=32][r=32/wave] ----------------
    short8 a2[2][2];
    #pragma unroll
    for (int nt = 0; nt < 2; ++nt)
      #pragma unroll
      for (int ks = 0; ks < 2; ++ks){
        int n2 = nt*16 + l15;
        int off = ((n2*128 + ks*64 + q*16) ^ ((n2 & 7) << 4)) >> 4;
        a2[nt][ks] = __builtin_bit_cast(short8, wb[512 + off]);
      }
    f32x4 acc2[2][2];
    #pragma unroll
    for (int nt = 0; nt < 2; ++nt)
      #pragma unroll
      for (int rt = 0; rt < 2; ++rt){
        acc2[nt][rt] = mfma16f(a2[nt][0], bh[rt][0], bias2[nt]);
        acc2[nt][rt] = mfma16f(a2[nt][1], bh[rt][1], acc2[nt][rt]);
      }

    // ---------------- layer 3: in-register dot + quarter-reduce ----------------
    #pragma unroll
    for (int rt = 0; rt < 2; ++rt){
      float p = 0.0f;
      #pragma unroll
      for (int nt = 0; nt < 2; ++nt)
        #pragma unroll
        for (int i = 0; i < 4; ++i)
          p = fmaf(fmaxf(acc2[nt][rt][i], 0.0f), w3f[nt][i], p);
      p += __shfl_xor(p, 16);
      p += __shfl_xor(p, 32);
      p += bias3;
      if (ln < 16)
        out[(rowBase + rt*16 + ln)*28 + g] = p;
    }

    // drain stage loads (had the whole compute phase to land), then barrier
    asm volatile("s_waitcnt vmcnt(0)" ::: "memory");
    __syncthreads();
  }
}

extern "C" void kernel_launch(void* const* d_in, const int* in_sizes, int n_in,
                              void* d_out, int out_size, void* d_ws, size_t ws_size,
                              hipStream_t stream){
  const float* x  = (const float*)d_in[0];
  const float* W1 = (const float*)d_in[1];
  const float* b1 = (const float*)d_in[2];
  const float* W2 = (const float*)d_in[3];
  const float* b2 = (const float*)d_in[4];
  const float* W3 = (const float*)d_in[5];
  const float* b3 = (const float*)d_in[6];
  unsigned char* ws = (unsigned char*)d_ws;
  float* out = (float*)d_out;
  if (ws_size < (size_t)WS_BYTES) return;
  hipLaunchKernelGGL(prep_weights, dim3(GN), dim3(256), 0, stream, W1, W2, ws);
  hipLaunchKernelGGL(mlp_fused, dim3(1024), dim3(256), 0, stream,
                     x, b1, b2, W3, b3, ws, out);
}